// Round 3
// baseline (2097.249 us; speedup 1.0000x reference)
//
#include <hip/hip_runtime.h>
#include <hip/hip_bf16.h>

#define NODES 100000
#define EDGES 1600000
#define FEAT 512
#define HID 128
#define NCLS 40
#define NPAD 48   // NCLS padded to 3 MFMA n-tiles

typedef __bf16 bf16x8 __attribute__((ext_vector_type(8)));
typedef float f32x4 __attribute__((ext_vector_type(4)));

static __device__ inline __bf16 cvt_bf16(float f) {
  union { __hip_bfloat16 h; __bf16 b; } u;
  u.h = __float2bfloat16(f);
  return u.b;
}

// ---------------- degree / norm ----------------
__global__ void deg_kernel(const int* __restrict__ ei, float* __restrict__ deg) {
  int e = blockIdx.x * blockDim.x + threadIdx.x;
  if (e < EDGES) atomicAdd(&deg[ei[EDGES + e]], 1.0f);
}

__global__ void dinv_kernel(float* __restrict__ deg) {
  int i = blockIdx.x * blockDim.x + threadIdx.x;
  if (i < NODES) deg[i] = rsqrtf(deg[i] + 1.0f);  // +1 = self loop
}

// ---------------- weight transposes (f32 -> bf16) ----------------
__global__ void tr_w1(const float* __restrict__ w1, __hip_bfloat16* __restrict__ w1t) {
  int idx = blockIdx.x * blockDim.x + threadIdx.x;  // over FEAT*HID
  if (idx >= FEAT * HID) return;
  int k = idx / HID, n = idx % HID;
  w1t[n * FEAT + k] = __float2bfloat16(w1[idx]);
}

__global__ void tr_w2(const float* __restrict__ w2, __hip_bfloat16* __restrict__ w2t) {
  int idx = blockIdx.x * blockDim.x + threadIdx.x;  // over NPAD*HID
  if (idx >= NPAD * HID) return;
  int n = idx / HID, k = idx % HID;
  w2t[n * HID + k] = (n < NCLS) ? __float2bfloat16(w2[k * NCLS + n]) : __float2bfloat16(0.0f);
}

// ---------------- GEMM1: h0[N,128] = x[N,512] @ W1 (A f32 -> bf16 in-reg) ----------------
__global__ __launch_bounds__(256) void gemm1_kernel(const float* __restrict__ x,
                                                    const __hip_bfloat16* __restrict__ w1t,
                                                    __hip_bfloat16* __restrict__ h0) {
  int wave = threadIdx.x >> 6;
  int lane = threadIdx.x & 63;
  int m0 = (blockIdx.x * 4 + wave) * 16;
  if (m0 >= NODES) return;
  int r = lane & 15, quad = lane >> 4;
  const float* arow = x + (size_t)(m0 + r) * FEAT + quad * 8;
  f32x4 acc[8];
#pragma unroll
  for (int n = 0; n < 8; n++) acc[n] = (f32x4){0.f, 0.f, 0.f, 0.f};
#pragma unroll
  for (int k0 = 0; k0 < FEAT; k0 += 32) {
    f32x4 a0 = *(const f32x4*)(arow + k0);
    f32x4 a1 = *(const f32x4*)(arow + k0 + 4);
    bf16x8 a;
    a[0] = cvt_bf16(a0[0]); a[1] = cvt_bf16(a0[1]);
    a[2] = cvt_bf16(a0[2]); a[3] = cvt_bf16(a0[3]);
    a[4] = cvt_bf16(a1[0]); a[5] = cvt_bf16(a1[1]);
    a[6] = cvt_bf16(a1[2]); a[7] = cvt_bf16(a1[3]);
#pragma unroll
    for (int n = 0; n < 8; n++) {
      const bf16x8* brow = (const bf16x8*)(w1t + (size_t)(n * 16 + r) * FEAT + k0 + quad * 8);
      acc[n] = __builtin_amdgcn_mfma_f32_16x16x32_bf16(a, *brow, acc[n], 0, 0, 0);
    }
  }
#pragma unroll
  for (int n = 0; n < 8; n++)
#pragma unroll
    for (int rr = 0; rr < 4; rr++) {
      int row = m0 + quad * 4 + rr;
      h0[(size_t)row * HID + n * 16 + r] = __float2bfloat16(acc[n][rr]);
    }
}

// ---------------- edge aggregation 1 (128 feat, atomics) ----------------
__global__ void agg1_kernel(const int* __restrict__ ei, const float* __restrict__ dinv,
                            const __hip_bfloat16* __restrict__ h0, float* __restrict__ agg1) {
  int tid = blockIdx.x * blockDim.x + threadIdx.x;
  int e = tid >> 6;
  int lane = tid & 63;
  if (e >= EDGES) return;
  int s = ei[e], d = ei[EDGES + e];
  float nrm = dinv[s] * dinv[d];
  const __hip_bfloat162* hrow = (const __hip_bfloat162*)(h0 + (size_t)s * HID);
  __hip_bfloat162 v = hrow[lane];
  float2 f = __bfloat1622float2(v);
  float* arow = agg1 + (size_t)d * HID + lane * 2;
  atomicAdd(arow, f.x * nrm);
  atomicAdd(arow + 1, f.y * nrm);
}

// ---------------- epilogue 1: h = relu(agg1 + h0*dinv^2 + b1), in place into h0 ----------------
__global__ void epi1_kernel(const float* __restrict__ agg1, const float* __restrict__ dinv,
                            const float* __restrict__ b1, __hip_bfloat16* __restrict__ h0) {
  int idx = blockIdx.x * blockDim.x + threadIdx.x;
  if (idx >= NODES * HID) return;
  int i = idx / HID, c = idx % HID;
  float di = dinv[i];
  float v = agg1[idx] + __bfloat162float(h0[idx]) * di * di + b1[c];
  h0[idx] = __float2bfloat16(fmaxf(v, 0.0f));
}

// ---------------- GEMM2: h1[N,40] = h[N,128] @ W2 ----------------
__global__ __launch_bounds__(256) void gemm2_kernel(const __hip_bfloat16* __restrict__ h,
                                                    const __hip_bfloat16* __restrict__ w2t,
                                                    float* __restrict__ h1) {
  int wave = threadIdx.x >> 6;
  int lane = threadIdx.x & 63;
  int m0 = (blockIdx.x * 4 + wave) * 16;
  if (m0 >= NODES) return;
  int r = lane & 15, quad = lane >> 4;
  const bf16x8* arow = (const bf16x8*)(h + (size_t)(m0 + r) * HID + quad * 8);
  f32x4 acc[3];
#pragma unroll
  for (int n = 0; n < 3; n++) acc[n] = (f32x4){0.f, 0.f, 0.f, 0.f};
#pragma unroll
  for (int k0 = 0; k0 < HID; k0 += 32) {
    bf16x8 a = arow[k0 / 8];
#pragma unroll
    for (int n = 0; n < 3; n++) {
      const bf16x8* brow = (const bf16x8*)(w2t + (size_t)(n * 16 + r) * HID + k0 + quad * 8);
      acc[n] = __builtin_amdgcn_mfma_f32_16x16x32_bf16(a, *brow, acc[n], 0, 0, 0);
    }
  }
#pragma unroll
  for (int n = 0; n < 3; n++)
#pragma unroll
    for (int rr = 0; rr < 4; rr++) {
      int col = n * 16 + r;
      if (col < NCLS) h1[(size_t)(m0 + quad * 4 + rr) * NCLS + col] = acc[n][rr];
    }
}

// ---------------- edge aggregation 2 (40 cls, atomics) ----------------
__global__ void agg2_kernel(const int* __restrict__ ei, const float* __restrict__ dinv,
                            const float* __restrict__ h1, float* __restrict__ agg2) {
  int tid = blockIdx.x * blockDim.x + threadIdx.x;
  int e = tid >> 6;
  int lane = tid & 63;
  if (e >= EDGES) return;
  int s = ei[e], d = ei[EDGES + e];
  float nrm = dinv[s] * dinv[d];
  if (lane < NCLS) atomicAdd(&agg2[(size_t)d * NCLS + lane], h1[(size_t)s * NCLS + lane] * nrm);
}

// ---------------- epilogue 2: bias + self loop + log_softmax (f32 output) ----------------
__global__ void epi2_kernel(const float* __restrict__ agg2, const float* __restrict__ h1,
                            const float* __restrict__ dinv, const float* __restrict__ b2,
                            float* __restrict__ out) {
  int tid = blockIdx.x * blockDim.x + threadIdx.x;
  int node = tid >> 6;
  int lane = tid & 63;
  if (node >= NODES) return;
  float di = dinv[node];
  float v = 0.0f, l = -1e30f;
  if (lane < NCLS) {
    v = agg2[(size_t)node * NCLS + lane] + h1[(size_t)node * NCLS + lane] * di * di + b2[lane];
    l = v;
  }
  float m = l;
#pragma unroll
  for (int o = 32; o > 0; o >>= 1) m = fmaxf(m, __shfl_xor(m, o));
  float ex = (lane < NCLS) ? expf(v - m) : 0.0f;
  float ssum = ex;
#pragma unroll
  for (int o = 32; o > 0; o >>= 1) ssum += __shfl_xor(ssum, o);
  if (lane < NCLS) out[(size_t)node * NCLS + lane] = v - m - logf(ssum);
}

extern "C" void kernel_launch(void* const* d_in, const int* in_sizes, int n_in,
                              void* d_out, int out_size, void* d_ws, size_t ws_size,
                              hipStream_t stream) {
  const float* x  = (const float*)d_in[0];
  const int* ei   = (const int*)d_in[1];
  const float* W1 = (const float*)d_in[2];
  const float* b1 = (const float*)d_in[3];
  const float* W2 = (const float*)d_in[4];
  const float* b2 = (const float*)d_in[5];
  float* out = (float*)d_out;

  char* ws = (char*)d_ws;
  float* dinv          = (float*)(ws + 0);                         // 400 KB
  __hip_bfloat16* w1t  = (__hip_bfloat16*)(ws + (1 << 20));        // 128 KB
  __hip_bfloat16* w2t  = (__hip_bfloat16*)(ws + (1 << 20) + 131072);
  __hip_bfloat16* h0   = (__hip_bfloat16*)(ws + (2 << 20));        // 25.6 MB
  float* agg1          = (float*)(ws + (size_t)28 * (1 << 20));    // 51.2 MB (28..79.2 MB)
  float* h1            = agg1;                                     // alias (agg1 dead after epi1), 16 MB
  float* agg2          = (float*)(ws + (size_t)48 * (1 << 20));    // 16 MB (48..64 MB)

  hipMemsetAsync(dinv, 0, (size_t)NODES * 4, stream);
  hipMemsetAsync(agg1, 0, (size_t)NODES * HID * 4, stream);

  deg_kernel<<<(EDGES + 255) / 256, 256, 0, stream>>>(ei, dinv);
  dinv_kernel<<<(NODES + 255) / 256, 256, 0, stream>>>(dinv);
  tr_w1<<<(FEAT * HID + 255) / 256, 256, 0, stream>>>(W1, w1t);
  tr_w2<<<(NPAD * HID + 255) / 256, 256, 0, stream>>>(W2, w2t);

  gemm1_kernel<<<(NODES / 16 + 3) / 4, 256, 0, stream>>>(x, w1t, h0);
  agg1_kernel<<<(size_t)EDGES * 64 / 256, 256, 0, stream>>>(ei, dinv, h0, agg1);
  epi1_kernel<<<(NODES * HID + 255) / 256, 256, 0, stream>>>(agg1, dinv, b1, h0);

  hipMemsetAsync(agg2, 0, (size_t)NODES * NCLS * 4, stream);
  gemm2_kernel<<<(NODES / 16 + 3) / 4, 256, 0, stream>>>(h0, w2t, h1);
  agg2_kernel<<<(size_t)EDGES * 64 / 256, 256, 0, stream>>>(ei, dinv, h1, agg2);
  epi2_kernel<<<((size_t)NODES * 64 + 255) / 256, 256, 0, stream>>>(agg2, h1, dinv, b2, out);
}

// Round 5
// 738.882 us; speedup vs baseline: 2.8384x; 2.8384x over previous
//
#include <hip/hip_runtime.h>
#include <hip/hip_bf16.h>

#define NODES 100000
#define EDGES 1600000
#define FEAT 512
#define HID 128
#define NCLS 40
#define NPAD 48                      // NCLS padded to 3 MFMA n-tiles
#define NBLK ((NODES + 255) / 256)   // 391 scan blocks

typedef __bf16 bf16x8 __attribute__((ext_vector_type(8)));
typedef float f32x4 __attribute__((ext_vector_type(4)));

static __device__ inline __bf16 cvt_bf16(float f) {
  union { __hip_bfloat16 h; __bf16 b; } u;
  u.h = __float2bfloat16(f);
  return u.b;
}

static __device__ inline __hip_bfloat162 pack_bf162(float a, float b) {
  __hip_bfloat162 r;
  r.x = __float2bfloat16(a);
  r.y = __float2bfloat16(b);
  return r;
}

// ---------------- degree (int) / norm ----------------
__global__ void deg_kernel(const int* __restrict__ ei, int* __restrict__ deg) {
  int e = blockIdx.x * blockDim.x + threadIdx.x;
  if (e < EDGES) atomicAdd(&deg[ei[EDGES + e]], 1);
}

__global__ void dinv_kernel(const int* __restrict__ deg, float* __restrict__ dinv) {
  int i = blockIdx.x * blockDim.x + threadIdx.x;
  if (i < NODES) dinv[i] = rsqrtf((float)deg[i] + 1.0f);  // +1 = self loop
}

// ---------------- CSR build: 3-kernel exclusive scan + scatter ----------------
__global__ void scan1_kernel(const int* __restrict__ deg, int* __restrict__ row_start,
                             int* __restrict__ blk) {
  __shared__ int tmp[256];
  int i = blockIdx.x * 256 + threadIdx.x;
  int v = (i < NODES) ? deg[i] : 0;
  tmp[threadIdx.x] = v;
  __syncthreads();
#pragma unroll
  for (int off = 1; off < 256; off <<= 1) {
    int t = 0;
    if (threadIdx.x >= off) t = tmp[threadIdx.x - off];
    __syncthreads();
    if (threadIdx.x >= off) tmp[threadIdx.x] += t;
    __syncthreads();
  }
  if (i < NODES) row_start[i] = tmp[threadIdx.x] - v;  // block-local exclusive
  if (threadIdx.x == 255) blk[blockIdx.x] = tmp[255];
}

__global__ void scan2_kernel(const int* __restrict__ blk, int* __restrict__ blk_off) {
  __shared__ int tmp[512];
  int i = threadIdx.x;
  int v = (i < NBLK) ? blk[i] : 0;
  tmp[i] = v;
  __syncthreads();
#pragma unroll
  for (int off = 1; off < 512; off <<= 1) {
    int t = 0;
    if (i >= off) t = tmp[i - off];
    __syncthreads();
    if (i >= off) tmp[i] += t;
    __syncthreads();
  }
  if (i < NBLK) blk_off[i] = tmp[i] - v;
}

__global__ void scan3_kernel(const int* __restrict__ blk_off, int* __restrict__ row_start,
                             int* __restrict__ cursor) {
  int i = blockIdx.x * 256 + threadIdx.x;
  if (i >= NODES) return;
  int rs = row_start[i] + blk_off[i >> 8];
  row_start[i] = rs;
  cursor[i] = rs;
}

__global__ void scatter_kernel(const int* __restrict__ ei, int* __restrict__ cursor,
                               int* __restrict__ adj) {
  int e = blockIdx.x * blockDim.x + threadIdx.x;
  if (e >= EDGES) return;
  int s = ei[e], d = ei[EDGES + e];
  int pos = atomicAdd(&cursor[d], 1);
  adj[pos] = s;
}

// ---------------- weight transposes (f32 -> bf16) ----------------
__global__ void tr_w1(const float* __restrict__ w1, __hip_bfloat16* __restrict__ w1t) {
  int idx = blockIdx.x * blockDim.x + threadIdx.x;  // over FEAT*HID
  if (idx >= FEAT * HID) return;
  int k = idx / HID, n = idx % HID;
  w1t[n * FEAT + k] = __float2bfloat16(w1[idx]);
}

__global__ void tr_w2(const float* __restrict__ w2, __hip_bfloat16* __restrict__ w2t) {
  int idx = blockIdx.x * blockDim.x + threadIdx.x;  // over NPAD*HID
  if (idx >= NPAD * HID) return;
  int n = idx / HID, k = idx % HID;
  w2t[n * HID + k] = (n < NCLS) ? __float2bfloat16(w2[k * NCLS + n]) : __float2bfloat16(0.0f);
}

// ---------------- GEMM1: h0[N,128] = x[N,512] @ W1 (A f32 -> bf16 in-reg) ----------------
__global__ __launch_bounds__(256) void gemm1_kernel(const float* __restrict__ x,
                                                    const __hip_bfloat16* __restrict__ w1t,
                                                    __hip_bfloat16* __restrict__ h0) {
  int wave = threadIdx.x >> 6;
  int lane = threadIdx.x & 63;
  int m0 = (blockIdx.x * 4 + wave) * 16;
  if (m0 >= NODES) return;
  int r = lane & 15, quad = lane >> 4;
  const float* arow = x + (size_t)(m0 + r) * FEAT + quad * 8;
  f32x4 acc[8];
#pragma unroll
  for (int n = 0; n < 8; n++) acc[n] = (f32x4){0.f, 0.f, 0.f, 0.f};
#pragma unroll
  for (int k0 = 0; k0 < FEAT; k0 += 32) {
    f32x4 a0 = *(const f32x4*)(arow + k0);
    f32x4 a1 = *(const f32x4*)(arow + k0 + 4);
    bf16x8 a;
    a[0] = cvt_bf16(a0[0]); a[1] = cvt_bf16(a0[1]);
    a[2] = cvt_bf16(a0[2]); a[3] = cvt_bf16(a0[3]);
    a[4] = cvt_bf16(a1[0]); a[5] = cvt_bf16(a1[1]);
    a[6] = cvt_bf16(a1[2]); a[7] = cvt_bf16(a1[3]);
#pragma unroll
    for (int n = 0; n < 8; n++) {
      const bf16x8* brow = (const bf16x8*)(w1t + (size_t)(n * 16 + r) * FEAT + k0 + quad * 8);
      acc[n] = __builtin_amdgcn_mfma_f32_16x16x32_bf16(a, *brow, acc[n], 0, 0, 0);
    }
  }
#pragma unroll
  for (int n = 0; n < 8; n++)
#pragma unroll
    for (int rr = 0; rr < 4; rr++) {
      int row = m0 + quad * 4 + rr;
      h0[(size_t)row * HID + n * 16 + r] = __float2bfloat16(acc[n][rr]);
    }
}

// ---------------- fused agg1 + epilogue1: h = relu(sum_nbrs + self + b1) ----------------
__global__ __launch_bounds__(256) void agg1_fused(
    const int* __restrict__ row_start, const int* __restrict__ deg,
    const int* __restrict__ adj, const float* __restrict__ dinv,
    const float* __restrict__ b1, const __hip_bfloat16* __restrict__ h0,
    __hip_bfloat16* __restrict__ h) {
  int wave = threadIdx.x >> 6, lane = threadIdx.x & 63;
  int node = blockIdx.x * 4 + wave;
  if (node >= NODES) return;
  float di = dinv[node];
  float2 f = __bfloat1622float2(((const __hip_bfloat162*)(h0 + (size_t)node * HID))[lane]);
  float ax = f.x * di * di, ay = f.y * di * di;  // self loop
  int start = row_start[node], end = start + deg[node];
  int p = start;
  for (; p + 4 <= end; p += 4) {
    int s0 = adj[p], s1 = adj[p + 1], s2 = adj[p + 2], s3 = adj[p + 3];
    float n0 = dinv[s0] * di, n1 = dinv[s1] * di, n2 = dinv[s2] * di, n3 = dinv[s3] * di;
    float2 v0 = __bfloat1622float2(((const __hip_bfloat162*)(h0 + (size_t)s0 * HID))[lane]);
    float2 v1 = __bfloat1622float2(((const __hip_bfloat162*)(h0 + (size_t)s1 * HID))[lane]);
    float2 v2 = __bfloat1622float2(((const __hip_bfloat162*)(h0 + (size_t)s2 * HID))[lane]);
    float2 v3 = __bfloat1622float2(((const __hip_bfloat162*)(h0 + (size_t)s3 * HID))[lane]);
    ax += v0.x * n0 + v1.x * n1 + v2.x * n2 + v3.x * n3;
    ay += v0.y * n0 + v1.y * n1 + v2.y * n2 + v3.y * n3;
  }
  for (; p < end; ++p) {
    int s = adj[p];
    float nrm = dinv[s] * di;
    float2 v = __bfloat1622float2(((const __hip_bfloat162*)(h0 + (size_t)s * HID))[lane]);
    ax += v.x * nrm;
    ay += v.y * nrm;
  }
  float2 b = ((const float2*)b1)[lane];
  ax = fmaxf(ax + b.x, 0.0f);
  ay = fmaxf(ay + b.y, 0.0f);
  ((__hip_bfloat162*)(h + (size_t)node * HID))[lane] = pack_bf162(ax, ay);
}

// ---------------- GEMM2: h1[N,40] = h[N,128] @ W2 ----------------
__global__ __launch_bounds__(256) void gemm2_kernel(const __hip_bfloat16* __restrict__ h,
                                                    const __hip_bfloat16* __restrict__ w2t,
                                                    float* __restrict__ h1) {
  int wave = threadIdx.x >> 6;
  int lane = threadIdx.x & 63;
  int m0 = (blockIdx.x * 4 + wave) * 16;
  if (m0 >= NODES) return;
  int r = lane & 15, quad = lane >> 4;
  const bf16x8* arow = (const bf16x8*)(h + (size_t)(m0 + r) * HID + quad * 8);
  f32x4 acc[3];
#pragma unroll
  for (int n = 0; n < 3; n++) acc[n] = (f32x4){0.f, 0.f, 0.f, 0.f};
#pragma unroll
  for (int k0 = 0; k0 < HID; k0 += 32) {
    bf16x8 a = arow[k0 / 8];
#pragma unroll
    for (int n = 0; n < 3; n++) {
      const bf16x8* brow = (const bf16x8*)(w2t + (size_t)(n * 16 + r) * HID + k0 + quad * 8);
      acc[n] = __builtin_amdgcn_mfma_f32_16x16x32_bf16(a, *brow, acc[n], 0, 0, 0);
    }
  }
#pragma unroll
  for (int n = 0; n < 3; n++)
#pragma unroll
    for (int rr = 0; rr < 4; rr++) {
      int col = n * 16 + r;
      if (col < NCLS) h1[(size_t)(m0 + quad * 4 + rr) * NCLS + col] = acc[n][rr];
    }
}

// ---------------- fused agg2 + bias + self loop + log_softmax ----------------
__global__ __launch_bounds__(256) void agg2_fused(
    const int* __restrict__ row_start, const int* __restrict__ deg,
    const int* __restrict__ adj, const float* __restrict__ dinv,
    const float* __restrict__ b2, const float* __restrict__ h1,
    float* __restrict__ out) {
  int wave = threadIdx.x >> 6, lane = threadIdx.x & 63;
  int node = blockIdx.x * 4 + wave;
  if (node >= NODES) return;
  float di = dinv[node];
  bool act = lane < NCLS;
  float acc = act ? h1[(size_t)node * NCLS + lane] * di * di : 0.0f;  // self loop
  int start = row_start[node], end = start + deg[node];
  int p = start;
  for (; p + 4 <= end; p += 4) {
    int s0 = adj[p], s1 = adj[p + 1], s2 = adj[p + 2], s3 = adj[p + 3];
    float n0 = dinv[s0] * di, n1 = dinv[s1] * di, n2 = dinv[s2] * di, n3 = dinv[s3] * di;
    if (act) {
      float v0 = h1[(size_t)s0 * NCLS + lane];
      float v1 = h1[(size_t)s1 * NCLS + lane];
      float v2 = h1[(size_t)s2 * NCLS + lane];
      float v3 = h1[(size_t)s3 * NCLS + lane];
      acc += v0 * n0 + v1 * n1 + v2 * n2 + v3 * n3;
    }
  }
  for (; p < end; ++p) {
    int s = adj[p];
    float nrm = dinv[s] * di;
    if (act) acc += h1[(size_t)s * NCLS + lane] * nrm;
  }
  float v = act ? acc + b2[lane] : -1e30f;
  float m = v;
#pragma unroll
  for (int o = 32; o > 0; o >>= 1) m = fmaxf(m, __shfl_xor(m, o));
  float ex = act ? expf(v - m) : 0.0f;
  float ssum = ex;
#pragma unroll
  for (int o = 32; o > 0; o >>= 1) ssum += __shfl_xor(ssum, o);
  if (act) out[(size_t)node * NCLS + lane] = v - m - logf(ssum);
}

extern "C" void kernel_launch(void* const* d_in, const int* in_sizes, int n_in,
                              void* d_out, int out_size, void* d_ws, size_t ws_size,
                              hipStream_t stream) {
  const float* x  = (const float*)d_in[0];
  const int* ei   = (const int*)d_in[1];
  const float* W1 = (const float*)d_in[2];
  const float* b1 = (const float*)d_in[3];
  const float* W2 = (const float*)d_in[4];
  const float* b2 = (const float*)d_in[5];
  float* out = (float*)d_out;

  char* ws = (char*)d_ws;
  int* deg_i          = (int*)(ws + 0);                    // 400 KB
  float* dinv         = (float*)(ws + (size_t)512 * 1024); // 400 KB
  int* row_start      = (int*)(ws + (size_t)1024 * 1024);  // 400 KB
  int* cursor         = (int*)(ws + (size_t)1536 * 1024);  // 400 KB
  int* blk            = (int*)(ws + (size_t)2048 * 1024);  // 2 KB
  int* blk_off        = (int*)(ws + (size_t)2052 * 1024);  // 2 KB
  int* adj            = (int*)(ws + (size_t)2560 * 1024);  // 6.4 MB -> ends ~8.9 MB
  __hip_bfloat16* w1t = (__hip_bfloat16*)(ws + (size_t)9728 * 1024);   // 128 KB
  __hip_bfloat16* w2t = (__hip_bfloat16*)(ws + (size_t)9856 * 1024);   // 12 KB
  __hip_bfloat16* h0  = (__hip_bfloat16*)(ws + (size_t)10 * 1048576);  // 25.6 MB -> ends 35.6
  __hip_bfloat16* h   = (__hip_bfloat16*)(ws + (size_t)36 * 1048576);  // 25.6 MB -> ends 61.6
  float* h1           = (float*)(ws + (size_t)10 * 1048576);           // alias h0 (dead after agg1_fused)

  (void)hipMemsetAsync(deg_i, 0, (size_t)NODES * 4, stream);

  deg_kernel<<<(EDGES + 255) / 256, 256, 0, stream>>>(ei, deg_i);
  dinv_kernel<<<(NODES + 255) / 256, 256, 0, stream>>>(deg_i, dinv);
  scan1_kernel<<<NBLK, 256, 0, stream>>>(deg_i, row_start, blk);
  scan2_kernel<<<1, 512, 0, stream>>>(blk, blk_off);
  scan3_kernel<<<NBLK, 256, 0, stream>>>(blk_off, row_start, cursor);
  scatter_kernel<<<(EDGES + 255) / 256, 256, 0, stream>>>(ei, cursor, adj);

  tr_w1<<<(FEAT * HID + 255) / 256, 256, 0, stream>>>(W1, w1t);
  tr_w2<<<(NPAD * HID + 255) / 256, 256, 0, stream>>>(W2, w2t);

  gemm1_kernel<<<(NODES / 16 + 3) / 4, 256, 0, stream>>>(x, w1t, h0);
  agg1_fused<<<(NODES + 3) / 4, 256, 0, stream>>>(row_start, deg_i, adj, dinv, b1, h0, h);
  gemm2_kernel<<<(NODES / 16 + 3) / 4, 256, 0, stream>>>(h, w2t, h1);
  agg2_fused<<<(NODES + 3) / 4, 256, 0, stream>>>(row_start, deg_i, adj, dinv, b2, h1, out);
}

// Round 6
// 696.219 us; speedup vs baseline: 3.0123x; 1.0613x over previous
//
#include <hip/hip_runtime.h>
#include <hip/hip_bf16.h>

#define NODES 100000
#define EDGES 1600000
#define FEAT 512
#define HID 128
#define NCLS 40
#define NPAD 48                      // NCLS padded to 3 MFMA n-tiles
#define NBLK ((NODES + 255) / 256)   // 391 scan blocks

typedef __bf16 bf16x8 __attribute__((ext_vector_type(8)));
typedef float f32x4 __attribute__((ext_vector_type(4)));

static __device__ inline __bf16 cvt_bf16(float f) {
  union { __hip_bfloat16 h; __bf16 b; } u;
  u.h = __float2bfloat16(f);
  return u.b;
}

static __device__ inline __hip_bfloat162 pack_bf162(float a, float b) {
  __hip_bfloat162 r;
  r.x = __float2bfloat16(a);
  r.y = __float2bfloat16(b);
  return r;
}

// ---------------- degree (int) / norm ----------------
__global__ void deg_kernel(const int* __restrict__ ei, int* __restrict__ deg) {
  int e = blockIdx.x * blockDim.x + threadIdx.x;
  if (e < EDGES) atomicAdd(&deg[ei[EDGES + e]], 1);
}

__global__ void dinv_kernel(const int* __restrict__ deg, float* __restrict__ dinv) {
  int i = blockIdx.x * blockDim.x + threadIdx.x;
  if (i < NODES) dinv[i] = rsqrtf((float)deg[i] + 1.0f);  // +1 = self loop
}

// ---------------- CSR build: 3-kernel exclusive scan + scatter ----------------
__global__ void scan1_kernel(const int* __restrict__ deg, int* __restrict__ row_start,
                             int* __restrict__ blk) {
  __shared__ int tmp[256];
  int i = blockIdx.x * 256 + threadIdx.x;
  int v = (i < NODES) ? deg[i] : 0;
  tmp[threadIdx.x] = v;
  __syncthreads();
#pragma unroll
  for (int off = 1; off < 256; off <<= 1) {
    int t = 0;
    if (threadIdx.x >= off) t = tmp[threadIdx.x - off];
    __syncthreads();
    if (threadIdx.x >= off) tmp[threadIdx.x] += t;
    __syncthreads();
  }
  if (i < NODES) row_start[i] = tmp[threadIdx.x] - v;  // block-local exclusive
  if (threadIdx.x == 255) blk[blockIdx.x] = tmp[255];
}

__global__ void scan2_kernel(const int* __restrict__ blk, int* __restrict__ blk_off) {
  __shared__ int tmp[512];
  int i = threadIdx.x;
  int v = (i < NBLK) ? blk[i] : 0;
  tmp[i] = v;
  __syncthreads();
#pragma unroll
  for (int off = 1; off < 512; off <<= 1) {
    int t = 0;
    if (i >= off) t = tmp[i - off];
    __syncthreads();
    if (i >= off) tmp[i] += t;
    __syncthreads();
  }
  if (i < NBLK) blk_off[i] = tmp[i] - v;
}

__global__ void scan3_kernel(const int* __restrict__ blk_off, int* __restrict__ row_start,
                             int* __restrict__ cursor) {
  int i = blockIdx.x * 256 + threadIdx.x;
  if (i >= NODES) return;
  int rs = row_start[i] + blk_off[i >> 8];
  row_start[i] = rs;
  cursor[i] = rs;
}

__global__ void scatter_kernel(const int* __restrict__ ei, int* __restrict__ cursor,
                               int* __restrict__ adj) {
  int e = blockIdx.x * blockDim.x + threadIdx.x;
  if (e >= EDGES) return;
  int s = ei[e], d = ei[EDGES + e];
  int pos = atomicAdd(&cursor[d], 1);
  adj[pos] = s;
}

// ---------------- weight transposes (f32 -> bf16) ----------------
__global__ void tr_w1(const float* __restrict__ w1, __hip_bfloat16* __restrict__ w1t) {
  int idx = blockIdx.x * blockDim.x + threadIdx.x;  // over FEAT*HID
  if (idx >= FEAT * HID) return;
  int k = idx / HID, n = idx % HID;
  w1t[n * FEAT + k] = __float2bfloat16(w1[idx]);
}

__global__ void tr_w2(const float* __restrict__ w2, __hip_bfloat16* __restrict__ w2t) {
  int idx = blockIdx.x * blockDim.x + threadIdx.x;  // over NPAD*HID
  if (idx >= NPAD * HID) return;
  int n = idx / HID, k = idx % HID;
  w2t[n * HID + k] = (n < NCLS) ? __float2bfloat16(w2[k * NCLS + n]) : __float2bfloat16(0.0f);
}

// ---------------- GEMM1 v2: 128x128 LDS-tiled, coalesced staging ----------------
// A: f32 global, staged coalesced -> bf16 XOR-swizzled LDS (conflict-free frag reads)
// B: w1t staged directly into MFMA fragment layout in LDS
__global__ __launch_bounds__(256) void gemm1_kernel(const float* __restrict__ x,
                                                    const __hip_bfloat16* __restrict__ w1t,
                                                    __hip_bfloat16* __restrict__ h0) {
  __shared__ __hip_bfloat16 Asw[128 * 128];  // 32 KB: [row][16B-chunk ^ (row&15)]
  __shared__ bf16x8 Bfrag[2048];             // 32 KB: [(n*4+ks)*64 + lane]
  int tid = threadIdx.x;
  int wave = tid >> 6, lane = tid & 63;
  int r = lane & 15, quad = lane >> 4;
  int m_base = blockIdx.x * 128;

  f32x4 acc[2][8];
#pragma unroll
  for (int mt = 0; mt < 2; mt++)
#pragma unroll
    for (int n = 0; n < 8; n++) acc[mt][n] = (f32x4){0.f, 0.f, 0.f, 0.f};

  for (int kc = 0; kc < FEAT; kc += 128) {
    __syncthreads();
    // stage A: 128 rows x 128 f32. thread -> (row, chunk cc): 16 threads/row,
    // each reads 32 B contiguous (512 B/row coalesced), converts, swizzled store.
#pragma unroll
    for (int rep = 0; rep < 8; rep++) {
      int f = tid + rep * 256;
      int row = f >> 4, cc = f & 15;
      int grow = m_base + row;
      f32x4 a0 = (f32x4){0.f, 0.f, 0.f, 0.f}, a1 = a0;
      if (grow < NODES) {
        const float* src = x + (size_t)grow * FEAT + kc + cc * 8;
        a0 = *(const f32x4*)src;
        a1 = *(const f32x4*)(src + 4);
      }
      bf16x8 b;
      b[0] = cvt_bf16(a0[0]); b[1] = cvt_bf16(a0[1]);
      b[2] = cvt_bf16(a0[2]); b[3] = cvt_bf16(a0[3]);
      b[4] = cvt_bf16(a1[0]); b[5] = cvt_bf16(a1[1]);
      b[6] = cvt_bf16(a1[2]); b[7] = cvt_bf16(a1[3]);
      *(bf16x8*)(Asw + row * 128 + ((cc ^ (row & 15)) * 8)) = b;
    }
    // stage B into fragment layout: frag f=(n,ks,lane): w1t[n*16+fr][kc+ks*32+fq*8]
#pragma unroll
    for (int rep = 0; rep < 8; rep++) {
      int f = tid + rep * 256;
      int fl = f & 63, ks = (f >> 6) & 3, n = f >> 8;
      int fr = fl & 15, fq = fl >> 4;
      Bfrag[f] = *(const bf16x8*)(w1t + (size_t)(n * 16 + fr) * FEAT + kc + ks * 32 + fq * 8);
    }
    __syncthreads();
    // compute: 4 k-steps x (2 m-tiles x 8 n-tiles)
#pragma unroll
    for (int ks = 0; ks < 4; ks++) {
      bf16x8 bf[8];
#pragma unroll
      for (int n = 0; n < 8; n++) bf[n] = Bfrag[(n * 4 + ks) * 64 + lane];
#pragma unroll
      for (int mt = 0; mt < 2; mt++) {
        int row = (wave * 2 + mt) * 16 + r;
        bf16x8 af = *(bf16x8*)(Asw + row * 128 + (((ks * 4 + quad) ^ r) * 8));
#pragma unroll
        for (int n = 0; n < 8; n++)
          acc[mt][n] = __builtin_amdgcn_mfma_f32_16x16x32_bf16(af, bf[n], acc[mt][n], 0, 0, 0);
      }
    }
  }
#pragma unroll
  for (int mt = 0; mt < 2; mt++) {
    int mrow = m_base + (wave * 2 + mt) * 16 + quad * 4;
#pragma unroll
    for (int n = 0; n < 8; n++)
#pragma unroll
      for (int rr = 0; rr < 4; rr++) {
        int row = mrow + rr;
        if (row < NODES) h0[(size_t)row * HID + n * 16 + r] = __float2bfloat16(acc[mt][n][rr]);
      }
  }
}

// ---------------- fused agg1 + epilogue1: h = relu(sum_nbrs + self + b1) ----------------
__global__ __launch_bounds__(256) void agg1_fused(
    const int* __restrict__ row_start, const int* __restrict__ deg,
    const int* __restrict__ adj, const float* __restrict__ dinv,
    const float* __restrict__ b1, const __hip_bfloat16* __restrict__ h0,
    __hip_bfloat16* __restrict__ h) {
  int wave = threadIdx.x >> 6, lane = threadIdx.x & 63;
  int node = blockIdx.x * 4 + wave;
  if (node >= NODES) return;
  float di = dinv[node];
  float2 f = __bfloat1622float2(((const __hip_bfloat162*)(h0 + (size_t)node * HID))[lane]);
  float ax = f.x * di * di, ay = f.y * di * di;  // self loop
  int start = row_start[node], end = start + deg[node];
  int p = start;
  for (; p + 8 <= end; p += 8) {
    int s[8];
    float nr[8];
    float2 v[8];
#pragma unroll
    for (int j = 0; j < 8; j++) s[j] = adj[p + j];
#pragma unroll
    for (int j = 0; j < 8; j++) nr[j] = dinv[s[j]] * di;
#pragma unroll
    for (int j = 0; j < 8; j++)
      v[j] = __bfloat1622float2(((const __hip_bfloat162*)(h0 + (size_t)s[j] * HID))[lane]);
#pragma unroll
    for (int j = 0; j < 8; j++) { ax += v[j].x * nr[j]; ay += v[j].y * nr[j]; }
  }
  for (; p < end; ++p) {
    int s = adj[p];
    float nrm = dinv[s] * di;
    float2 v = __bfloat1622float2(((const __hip_bfloat162*)(h0 + (size_t)s * HID))[lane]);
    ax += v.x * nrm;
    ay += v.y * nrm;
  }
  float2 b = ((const float2*)b1)[lane];
  ax = fmaxf(ax + b.x, 0.0f);
  ay = fmaxf(ay + b.y, 0.0f);
  ((__hip_bfloat162*)(h + (size_t)node * HID))[lane] = pack_bf162(ax, ay);
}

// ---------------- GEMM2: h1[N,40] = h[N,128] @ W2 ----------------
__global__ __launch_bounds__(256) void gemm2_kernel(const __hip_bfloat16* __restrict__ h,
                                                    const __hip_bfloat16* __restrict__ w2t,
                                                    float* __restrict__ h1) {
  int wave = threadIdx.x >> 6;
  int lane = threadIdx.x & 63;
  int m0 = (blockIdx.x * 4 + wave) * 16;
  if (m0 >= NODES) return;
  int r = lane & 15, quad = lane >> 4;
  const bf16x8* arow = (const bf16x8*)(h + (size_t)(m0 + r) * HID + quad * 8);
  f32x4 acc[3];
#pragma unroll
  for (int n = 0; n < 3; n++) acc[n] = (f32x4){0.f, 0.f, 0.f, 0.f};
#pragma unroll
  for (int k0 = 0; k0 < HID; k0 += 32) {
    bf16x8 a = arow[k0 / 8];
#pragma unroll
    for (int n = 0; n < 3; n++) {
      const bf16x8* brow = (const bf16x8*)(w2t + (size_t)(n * 16 + r) * HID + k0 + quad * 8);
      acc[n] = __builtin_amdgcn_mfma_f32_16x16x32_bf16(a, *brow, acc[n], 0, 0, 0);
    }
  }
#pragma unroll
  for (int n = 0; n < 3; n++)
#pragma unroll
    for (int rr = 0; rr < 4; rr++) {
      int col = n * 16 + r;
      if (col < NCLS) h1[(size_t)(m0 + quad * 4 + rr) * NCLS + col] = acc[n][rr];
    }
}

// ---------------- fused agg2 + bias + self loop + log_softmax ----------------
__global__ __launch_bounds__(256) void agg2_fused(
    const int* __restrict__ row_start, const int* __restrict__ deg,
    const int* __restrict__ adj, const float* __restrict__ dinv,
    const float* __restrict__ b2, const float* __restrict__ h1,
    float* __restrict__ out) {
  int wave = threadIdx.x >> 6, lane = threadIdx.x & 63;
  int node = blockIdx.x * 4 + wave;
  if (node >= NODES) return;
  float di = dinv[node];
  bool act = lane < NCLS;
  float acc = act ? h1[(size_t)node * NCLS + lane] * di * di : 0.0f;  // self loop
  int start = row_start[node], end = start + deg[node];
  int p = start;
  for (; p + 8 <= end; p += 8) {
    int s[8];
    float nr[8];
#pragma unroll
    for (int j = 0; j < 8; j++) s[j] = adj[p + j];
#pragma unroll
    for (int j = 0; j < 8; j++) nr[j] = dinv[s[j]] * di;
    if (act) {
      float v[8];
#pragma unroll
      for (int j = 0; j < 8; j++) v[j] = h1[(size_t)s[j] * NCLS + lane];
#pragma unroll
      for (int j = 0; j < 8; j++) acc += v[j] * nr[j];
    }
  }
  for (; p < end; ++p) {
    int s = adj[p];
    float nrm = dinv[s] * di;
    if (act) acc += h1[(size_t)s * NCLS + lane] * nrm;
  }
  float v = act ? acc + b2[lane] : -1e30f;
  float m = v;
#pragma unroll
  for (int o = 32; o > 0; o >>= 1) m = fmaxf(m, __shfl_xor(m, o));
  float ex = act ? expf(v - m) : 0.0f;
  float ssum = ex;
#pragma unroll
  for (int o = 32; o > 0; o >>= 1) ssum += __shfl_xor(ssum, o);
  if (act) out[(size_t)node * NCLS + lane] = v - m - logf(ssum);
}

extern "C" void kernel_launch(void* const* d_in, const int* in_sizes, int n_in,
                              void* d_out, int out_size, void* d_ws, size_t ws_size,
                              hipStream_t stream) {
  const float* x  = (const float*)d_in[0];
  const int* ei   = (const int*)d_in[1];
  const float* W1 = (const float*)d_in[2];
  const float* b1 = (const float*)d_in[3];
  const float* W2 = (const float*)d_in[4];
  const float* b2 = (const float*)d_in[5];
  float* out = (float*)d_out;

  char* ws = (char*)d_ws;
  int* deg_i          = (int*)(ws + 0);                    // 400 KB
  float* dinv         = (float*)(ws + (size_t)512 * 1024); // 400 KB
  int* row_start      = (int*)(ws + (size_t)1024 * 1024);  // 400 KB
  int* cursor         = (int*)(ws + (size_t)1536 * 1024);  // 400 KB
  int* blk            = (int*)(ws + (size_t)2048 * 1024);  // 2 KB
  int* blk_off        = (int*)(ws + (size_t)2052 * 1024);  // 2 KB
  int* adj            = (int*)(ws + (size_t)2560 * 1024);  // 6.4 MB -> ends ~8.9 MB
  __hip_bfloat16* w1t = (__hip_bfloat16*)(ws + (size_t)9728 * 1024);   // 128 KB
  __hip_bfloat16* w2t = (__hip_bfloat16*)(ws + (size_t)9856 * 1024);   // 12 KB
  __hip_bfloat16* h0  = (__hip_bfloat16*)(ws + (size_t)10 * 1048576);  // 25.6 MB -> ends 35.6
  __hip_bfloat16* h   = (__hip_bfloat16*)(ws + (size_t)36 * 1048576);  // 25.6 MB -> ends 61.6
  float* h1           = (float*)(ws + (size_t)10 * 1048576);           // alias h0 (dead after agg1_fused)

  (void)hipMemsetAsync(deg_i, 0, (size_t)NODES * 4, stream);

  deg_kernel<<<(EDGES + 255) / 256, 256, 0, stream>>>(ei, deg_i);
  dinv_kernel<<<(NODES + 255) / 256, 256, 0, stream>>>(deg_i, dinv);
  scan1_kernel<<<NBLK, 256, 0, stream>>>(deg_i, row_start, blk);
  scan2_kernel<<<1, 512, 0, stream>>>(blk, blk_off);
  scan3_kernel<<<NBLK, 256, 0, stream>>>(blk_off, row_start, cursor);
  scatter_kernel<<<(EDGES + 255) / 256, 256, 0, stream>>>(ei, cursor, adj);

  tr_w1<<<(FEAT * HID + 255) / 256, 256, 0, stream>>>(W1, w1t);
  tr_w2<<<(NPAD * HID + 255) / 256, 256, 0, stream>>>(W2, w2t);

  gemm1_kernel<<<(NODES + 127) / 128, 256, 0, stream>>>(x, w1t, h0);
  agg1_fused<<<(NODES + 3) / 4, 256, 0, stream>>>(row_start, deg_i, adj, dinv, b1, h0, h);
  gemm2_kernel<<<(NODES / 16 + 3) / 4, 256, 0, stream>>>(h, w2t, h1);
  agg2_fused<<<(NODES + 3) / 4, 256, 0, stream>>>(row_start, deg_i, adj, dinv, b2, h1, out);
}